// Round 8
// baseline (368.426 us; speedup 1.0000x reference)
//
#include <hip/hip_runtime.h>

// NHWC MFMA pipeline v4: deform = 36-iter K-loop (64ch/iter), depth-2 load
// pipeline, fused GN-stats atomics; coalesced prep/transpose helpers.
// ws: xT/out1 (NHWC bf16, alias) 8 MB | raw (NCHW bf16) 8 MB | wTg 1.18 MB |
//     tmtr 0.39 MB | stats 1 KB | flag 16 B | wT6 73,728 B  (~17.6 MiB)

typedef unsigned int u32;
typedef unsigned short u16;
typedef __attribute__((ext_vector_type(8))) short bf16x8;
typedef __attribute__((ext_vector_type(4))) float floatx4;

#define HW 4096
#define CHW 1048576

static __device__ __forceinline__ float bf2f(u16 u) {
    union { u32 i; float f; } c; c.i = ((u32)u) << 16; return c.f;
}
static __device__ __forceinline__ u16 f2bf(float f) {
    union { float f; u32 i; } c; c.f = f;
    u32 x = c.i;
    return (u16)((x + 0x7FFFu + ((x >> 16) & 1u)) >> 16);   // RNE
}
static __device__ __forceinline__ float loadv(const void* p, long i, int f32) {
    return f32 ? ((const float*)p)[i] : bf2f(((const u16*)p)[i]);
}

__global__ __launch_bounds__(256) void k_probe(const u32* __restrict__ xw,
                                               u32* __restrict__ flag) {
    __shared__ int cnt;
    if (threadIdx.x == 0) cnt = 0;
    __syncthreads();
    union { u32 i; float f; } c;
    c.i = xw[threadIdx.x * 997];
    float a = fabsf(c.f);
    if (a > 1e-8f && a < 1e4f) atomicAdd(&cnt, 1);
    __syncthreads();
    if (threadIdx.x == 0) { flag[0] = (cnt >= 128) ? 1u : 0u; flag[1] = 0u; }
}

// ---------------------------------------------------------------------------
// NCHW (flag dtype) -> NHWC bf16 via LDS transpose; fully coalesced.
// One block per (n,h).
// ---------------------------------------------------------------------------
__global__ __launch_bounds__(256) void k_to_nhwc(const void* __restrict__ src,
                                                 const u32* __restrict__ flag,
                                                 u16* __restrict__ dst) {
    __shared__ u16 T[64 * 258];
    const int f32 = (int)flag[0];
    const int bid = blockIdx.x;      // n*64 + h
    const int n = bid >> 6, h = bid & 63;
    const int tid = threadIdx.x;
    const long sb = (long)n * CHW + (h << 6);
    for (int it = 0; it < 64; ++it) {
        int e = it * 256 + tid;
        int c = e >> 6, w = e & 63;
        T[w * 258 + c] = f2bf(loadv(src, sb + (long)c * HW + w, f32));
    }
    __syncthreads();
    const int w = tid >> 2, cq = tid & 3;
    const u32* Tr = (const u32*)T;
    u16* ob = dst + (long)n * CHW + (long)((h << 6) + w) * 256 + cq * 64;
    #pragma unroll
    for (int s = 0; s < 8; ++s) {
        uint4 o;
        o.x = Tr[129 * w + 32 * cq + 4 * s + 0];
        o.y = Tr[129 * w + 32 * cq + 4 * s + 1];
        o.z = Tr[129 * w + 32 * cq + 4 * s + 2];
        o.w = Tr[129 * w + 32 * cq + 4 * s + 3];
        *(uint4*)&ob[s * 8] = o;
    }
}

// ---------------------------------------------------------------------------
// Pack deform weights (dest-indexed, coalesced u32 stores):
// wTg[(q*256 + o)*32 + c%32] <- w_dc[o][c][k],  q = k*8 + c/32.
// Block 0 also zeroes the GN-stats accumulator (runs before k_deform).
// ---------------------------------------------------------------------------
__global__ __launch_bounds__(256) void k_prep_w(const void* __restrict__ wdc,
                                                const u32* __restrict__ flag,
                                                u16* __restrict__ wTg,
                                                float* __restrict__ stats) {
    if (blockIdx.x == 0) stats[threadIdx.x] = 0.f;   // 256 floats
    const int f32 = (int)flag[0];
    int idx2 = blockIdx.x * 256 + threadIdx.x;       // 1152 blocks -> 294912
    int cp = idx2 & 15;
    int o  = (idx2 >> 4) & 255;
    int q  = idx2 >> 12;
    int k  = q >> 3;
    int c0 = ((q & 7) << 5) + (cp << 1);
    long s0 = (long)o * 2304 + c0 * 9 + k;
    u16 w0 = f2bf(loadv(wdc, s0, f32));
    u16 w1 = f2bf(loadv(wdc, s0 + 9, f32));
    ((u32*)wTg)[idx2] = (u32)w0 | ((u32)w1 << 16);
}

// ---------------------------------------------------------------------------
// Pack offset-conv weights: [oc][c][k] -> wT6[q][o(16)][c%32]
// ---------------------------------------------------------------------------
__global__ __launch_bounds__(256) void k_prep_w6(const void* __restrict__ w_tm,
                                                 const void* __restrict__ w_tr,
                                                 const u32* __restrict__ flag,
                                                 u16* __restrict__ wT6) {
    const int f32 = (int)flag[0];
    int i = blockIdx.x * 256 + threadIdx.x;   // 144 blocks = 36864
    int q  = i >> 9;
    int o  = (i >> 5) & 15;
    int cc = i & 31;
    int k  = q >> 3;
    int c  = ((q & 7) << 5) + cc;
    float v = 0.f;
    if (o < 4)      v = loadv(w_tm, (long)o * 2304 + c * 9 + k, f32);
    else if (o < 6) v = loadv(w_tr, (long)(o - 4) * 2304 + c * 9 + k, f32);
    wT6[i] = f2bf(v);
}

// ---------------------------------------------------------------------------
// MFMA offset conv: D[6][64] per (n,h) row.
// ---------------------------------------------------------------------------
__global__ __launch_bounds__(512) void k_conv6(
    const u16* __restrict__ srcT, const u16* __restrict__ wT6,
    const void* __restrict__ b_tm, const void* __restrict__ b_tr,
    const u32* __restrict__ flag,
    float* __restrict__ tmtr)
{
    __shared__ float red[8][64][17];
    const int tid = threadIdx.x;
    const int bid = blockIdx.x;
    const int n = bid >> 6, h = bid & 63;
    const int wv = tid >> 6;
    const int lane = tid & 63;
    const int quad = lane >> 4;
    const int l16 = lane & 15;
    const u16* sp = srcT + (long)n * CHW;

    floatx4 acc[4];
    #pragma unroll
    for (int j4 = 0; j4 < 4; ++j4) acc[j4] = (floatx4){0.f, 0.f, 0.f, 0.f};

    for (int qi = 0; qi < 9; ++qi) {
        const int q = wv * 9 + qi;
        const int k = q >> 3, cb = q & 7;
        const int ky = k / 3, kx = k % 3;
        const int row = h + ky - 1;
        const bool rv = (row >= 0) && (row < 64);
        bf16x8 av = *(const bf16x8*)&wT6[(((q << 4) + l16) << 5) + (quad << 3)];
        #pragma unroll
        for (int j4 = 0; j4 < 4; ++j4) {
            int w = (j4 << 4) + l16;
            int px = w + kx - 1;
            bf16x8 bv = {0, 0, 0, 0, 0, 0, 0, 0};
            if (rv && px >= 0 && px < 64)
                bv = *(const bf16x8*)&sp[(((long)(row << 6) + px) << 8) + (cb << 5) + (quad << 3)];
            acc[j4] = __builtin_amdgcn_mfma_f32_16x16x32_bf16(av, bv, acc[j4], 0, 0, 0);
        }
    }
    #pragma unroll
    for (int j4 = 0; j4 < 4; ++j4)
        #pragma unroll
        for (int r = 0; r < 4; ++r)
            red[wv][lane][(j4 << 2) + r] = acc[j4][r];
    __syncthreads();
    if (tid < 384) {
        const int o = tid >> 6, w = tid & 63;
        const int ln = ((o >> 2) << 4) + (w & 15);
        const int slot = ((w >> 4) << 2) + (o & 3);
        float s = 0.f;
        #pragma unroll
        for (int v = 0; v < 8; ++v) s += red[v][ln][slot];
        const int f32 = (int)flag[0];
        float bias = (o < 4) ? loadv(b_tm, o, f32) : loadv(b_tr, o - 4, f32);
        tmtr[((long)n * 6 + o) * HW + (h << 6) + w] = s + bias;
    }
}

// ---------------------------------------------------------------------------
// MFMA deform conv v4.  Grid 512: block = (n, h, px-half); 8 waves, each
// 32o x 32px.  36 iterations of 64 channels (2 chunks); depth-2 pipeline for
// sampled loads, depth-1 for A-frags (direct from L2).  GN stats fused via
// per-wave reduction + atomicAdd into stats[] (sum, sumsq per (n,group)).
// ---------------------------------------------------------------------------
__global__ __launch_bounds__(512, 4) void k_deform(
    const u16* __restrict__ srcT, const float* __restrict__ tmtr,
    const u16* __restrict__ wTg, u16* __restrict__ raw,
    float* __restrict__ stats)
{
    __shared__ __align__(16) short Sl[2][32 * 72];   // 9216 B
    __shared__ int   g_y0[288];
    __shared__ int   g_x0[288];
    __shared__ float g_wy[288];
    __shared__ float g_wx[288];

    const int tid = threadIdx.x;
    const int bid = blockIdx.x;                 // n*128 + h*2 + half
    const int n = bid >> 7, h = (bid >> 1) & 63, half = bid & 1;
    const float* tb = tmtr + (long)n * 6 * HW + (h << 6) + (half << 5);

    for (int i = tid; i < 288; i += 512) {      // geometry for 9k x 32px
        int k = i >> 5, ww2 = i & 31;
        float m00 = tb[ww2],          m01 = tb[HW + ww2];
        float m10 = tb[2 * HW + ww2], m11 = tb[3 * HW + ww2];
        float tr0 = tb[4 * HW + ww2], tr1 = tb[5 * HW + ww2];
        float ry = (float)(k / 3) - 1.f;
        float rx = (float)(k % 3) - 1.f;
        float dy = m00 * ry + m01 * rx - ry + tr0;
        float dx = m10 * ry + m11 * rx - rx + tr1;
        float py = (float)h + ry + dy;
        float px = (float)((half << 5) + ww2) + rx + dx;
        float y0f = floorf(py), x0f = floorf(px);
        g_y0[i] = (int)y0f; g_x0[i] = (int)x0f;
        g_wy[i] = py - y0f; g_wx[i] = px - x0f;
    }
    __syncthreads();

    const long nbase = (long)n * CHW;
    const u16* sp = srcT + nbase;
    const int sw  = tid >> 4;      // px 0..31
    const int scq = tid & 15;      // 4-channel group
    const int lane = tid & 63;
    const int quad = lane >> 4;
    const int l16  = lane & 15;
    const int o0   = (tid >> 6) << 5;

    floatx4 acc[2][2];
    #pragma unroll
    for (int i = 0; i < 2; ++i)
        #pragma unroll
        for (int j = 0; j < 2; ++j)
            acc[i][j] = (floatx4){0.f, 0.f, 0.f, 0.f};

    // per-k sampler state
    int a00 = 0, a01 = 0, a10 = 0, a11 = 0;
    float cw00 = 0.f, cw01 = 0.f, cw10 = 0.f, cw11 = 0.f;
    int cur_k = -1;

    uint2 rs0[4], rs1[4];            // two in-flight corner-load sets
    floatx4 cv0 = {0,0,0,0}, cv1 = {0,0,0,0};
    bf16x8 W0[4], W1[4];

    auto issueS = [&](int t, uint2* r, floatx4* cwv) {
        const int k = t >> 2;
        if (k != cur_k) {
            cur_k = k;
            int gi = (k << 5) + sw;
            int y0 = g_y0[gi], x0 = g_x0[gi];
            float wy1 = g_wy[gi], wx1 = g_wx[gi];
            float wy0 = 1.f - wy1, wx0 = 1.f - wx1;
            bool yv0 = (y0 >= 0) && (y0 < 64);
            bool yv1 = (y0 >= -1) && (y0 < 63);
            bool xv0 = (x0 >= 0) && (x0 < 64);
            bool xv1 = (x0 >= -1) && (x0 < 63);
            int yc0 = min(max(y0, 0), 63),     yc1 = min(max(y0 + 1, 0), 63);
            int xc0 = min(max(x0, 0), 63),     xc1 = min(max(x0 + 1, 0), 63);
            a00 = yc0 * 64 + xc0; a01 = yc0 * 64 + xc1;
            a10 = yc1 * 64 + xc0; a11 = yc1 * 64 + xc1;
            cw00 = (yv0 && xv0) ? wy0 * wx0 : 0.f;
            cw01 = (yv0 && xv1) ? wy0 * wx1 : 0.f;
            cw10 = (yv1 && xv0) ? wy1 * wx0 : 0.f;
            cw11 = (yv1 && xv1) ? wy1 * wx1 : 0.f;
        }
        *cwv = (floatx4){cw00, cw01, cw10, cw11};
        const int cc = ((t & 3) << 6) + (scq << 2);    // 4 channels
        r[0] = *(const uint2*)&sp[(long)a00 * 256 + cc];
        r[1] = *(const uint2*)&sp[(long)a01 * 256 + cc];
        r[2] = *(const uint2*)&sp[(long)a10 * 256 + cc];
        r[3] = *(const uint2*)&sp[(long)a11 * 256 + cc];
    };
    auto publish = [&](const uint2* r, floatx4 cwv, int b) {
        u32 pk[2];
        #pragma unroll
        for (int hh = 0; hh < 2; ++hh) {
            u32 w00 = hh ? r[0].y : r[0].x;
            u32 w01 = hh ? r[1].y : r[1].x;
            u32 w10 = hh ? r[2].y : r[2].x;
            u32 w11 = hh ? r[3].y : r[3].x;
            float a = fmaf(cwv[0], bf2f((u16)w00), fmaf(cwv[1], bf2f((u16)w01),
                      fmaf(cwv[2], bf2f((u16)w10), cwv[3] * bf2f((u16)w11))));
            float bb = fmaf(cwv[0], bf2f((u16)(w00 >> 16)), fmaf(cwv[1], bf2f((u16)(w01 >> 16)),
                       fmaf(cwv[2], bf2f((u16)(w10 >> 16)), cwv[3] * bf2f((u16)(w11 >> 16)))));
            pk[hh] = (u32)f2bf(a) | ((u32)f2bf(bb) << 16);
        }
        *(uint2*)&Sl[b][sw * 72 + (scq << 2)] = make_uint2(pk[0], pk[1]);
    };
    auto loadW = [&](int t, bf16x8* W) {
        int q0 = ((t >> 2) << 3) + ((t & 3) << 1);
        const u16* wp = wTg + (((size_t)q0 * 256 + o0 + l16) << 5) + (quad << 3);
        W[0] = *(const bf16x8*)wp;
        W[1] = *(const bf16x8*)(wp + (16 << 5));
        W[2] = *(const bf16x8*)(wp + (256 << 5));
        W[3] = *(const bf16x8*)(wp + (272 << 5));
    };
    auto compute = [&](const bf16x8* W, int b) {
        #pragma unroll
        for (int j = 0; j < 2; ++j) {
            const short* base = &Sl[b][((j << 4) + l16) * 72 + (quad << 3)];
            bf16x8 B0 = *(const bf16x8*)base;
            bf16x8 B1 = *(const bf16x8*)(base + 32);
            acc[0][j] = __builtin_amdgcn_mfma_f32_16x16x32_bf16(W[0], B0, acc[0][j], 0, 0, 0);
            acc[1][j] = __builtin_amdgcn_mfma_f32_16x16x32_bf16(W[1], B0, acc[1][j], 0, 0, 0);
            acc[0][j] = __builtin_amdgcn_mfma_f32_16x16x32_bf16(W[2], B1, acc[0][j], 0, 0, 0);
            acc[1][j] = __builtin_amdgcn_mfma_f32_16x16x32_bf16(W[3], B1, acc[1][j], 0, 0, 0);
        }
    };

    // prologue: Sl[0] <- iter 0; rs1 <- iter 1 loads; W0/W1 <- iters 0/1
    issueS(0, rs0, &cv0);
    publish(rs0, cv0, 0);
    issueS(1, rs1, &cv1);
    loadW(0, W0);
    loadW(1, W1);
    __syncthreads();

    for (int p = 0; p < 18; ++p) {
        const int t = p << 1;
        // even iter t: compute Sl[0], publish t+1 into Sl[1]
        if (t + 2 < 36) issueS(t + 2, rs0, &cv0);
        compute(W0, 0);
        if (t + 2 < 36) loadW(t + 2, W0);
        publish(rs1, cv1, 1);
        __syncthreads();
        // odd iter t+1: compute Sl[1], publish t+2 into Sl[0]
        if (t + 3 < 36) issueS(t + 3, rs1, &cv1);
        compute(W1, 1);
        if (t + 3 < 36) loadW(t + 3, W1);
        if (t + 2 < 36) publish(rs0, cv0, 0);
        __syncthreads();
    }

    // fused GN statistics: per-wave reduce fp32 accs -> atomicAdd sum/sumsq
    #pragma unroll
    for (int i = 0; i < 2; ++i) {
        float s1 = 0.f, s2 = 0.f;
        #pragma unroll
        for (int j = 0; j < 2; ++j)
            #pragma unroll
            for (int r = 0; r < 4; ++r) {
                float v = acc[i][j][r];
                s1 += v; s2 += v * v;
            }
        #pragma unroll
        for (int off = 1; off <= 16; off <<= 1) {
            s1 += __shfl_xor(s1, off, 64);
            s2 += __shfl_xor(s2, off, 64);
        }
        if ((lane & 31) == 0) {
            int g = (o0 >> 3) + 2 * i + (lane >> 5);
            atomicAdd(&stats[(n * 32 + g) * 2], s1);
            atomicAdd(&stats[(n * 32 + g) * 2 + 1], s2);
        }
    }

    // epilogue: o = o0 + i*16 + quad*4 + r, w = half*32 + j*16 + l16
    #pragma unroll
    for (int i = 0; i < 2; ++i)
        #pragma unroll
        for (int j = 0; j < 2; ++j)
            #pragma unroll
            for (int r = 0; r < 4; ++r) {
                int o = o0 + i * 16 + quad * 4 + r;
                raw[nbase + ((long)o << 12) + (h << 6) + (half << 5) + (j << 4) + l16]
                    = f2bf(acc[i][j][r]);
            }
}

// ---------------------------------------------------------------------------
// GN + relu; raw (NCHW bf16) -> out1 (NHWC bf16) via LDS transpose.
// stats[] holds raw (sum, sumsq).
// ---------------------------------------------------------------------------
__global__ __launch_bounds__(256) void k_gn_relu(
    const u16* __restrict__ raw, const float* __restrict__ stats,
    const void* __restrict__ gamma, const void* __restrict__ beta,
    const u32* __restrict__ flag,
    u16* __restrict__ out1)
{
    __shared__ u16 T[64 * 258];
    const int f32 = (int)flag[0];
    const int bid = blockIdx.x;
    const int n = bid >> 6, h = bid & 63;
    const int tid = threadIdx.x;
    const u16* rb = raw + (long)n * CHW + (h << 6);
    for (int it = 0; it < 64; ++it) {
        int e = it * 256 + tid;
        int c = e >> 6, w = e & 63;
        int ng = n * 32 + (c >> 3);
        float mean = stats[ng * 2] * (1.f / 32768.f);
        float var  = stats[ng * 2 + 1] * (1.f / 32768.f) - mean * mean;
        float rstd = rsqrtf(var + 1e-5f);
        float ga = loadv(gamma, c, f32) * rstd;
        float be = loadv(beta, c, f32) - mean * ga;
        float v = fmaxf(fmaf(bf2f(rb[(long)c * HW + w]), ga, be), 0.f);
        T[w * 258 + c] = f2bf(v);
    }
    __syncthreads();
    const int w = tid >> 2, cq = tid & 3;
    const u32* Tr = (const u32*)T;
    u16* ob = out1 + (long)n * CHW + (long)((h << 6) + w) * 256 + cq * 64;
    #pragma unroll
    for (int s = 0; s < 8; ++s) {
        uint4 o;
        o.x = Tr[129 * w + 32 * cq + 4 * s + 0];
        o.y = Tr[129 * w + 32 * cq + 4 * s + 1];
        o.z = Tr[129 * w + 32 * cq + 4 * s + 2];
        o.w = Tr[129 * w + 32 * cq + 4 * s + 3];
        *(uint4*)&ob[s * 8] = o;
    }
}

// ---------------------------------------------------------------------------
__global__ __launch_bounds__(256) void k_gn_final(
    const u16* __restrict__ raw, const float* __restrict__ stats,
    const void* __restrict__ gamma, const void* __restrict__ beta,
    const void* __restrict__ x, const u32* __restrict__ flag,
    void* __restrict__ outp)
{
    const int f32 = (int)flag[0];
    const int i = blockIdx.x * 256 + threadIdx.x;
    const int e = i << 3;
    const int c = (e >> 12) & 255;
    const int ng = (e >> 20) * 32 + (c >> 3);
    float mean = stats[ng * 2] * (1.f / 32768.f);
    float var  = stats[ng * 2 + 1] * (1.f / 32768.f) - mean * mean;
    float rstd = rsqrtf(var + 1e-5f);
    float ga = loadv(gamma, c, f32) * rstd;
    float be = loadv(beta, c, f32) - mean * ga;
    uint4 p = ((const uint4*)raw)[i];
    u32 ww[4] = {p.x, p.y, p.z, p.w};
    float v[8];
    #pragma unroll
    for (int q = 0; q < 4; ++q) {
        v[2 * q + 0] = fmaxf(fmaf(bf2f((u16)(ww[q] & 0xFFFFu)), ga, be) + loadv(x, (long)e + 2 * q + 0, f32), 0.f);
        v[2 * q + 1] = fmaxf(fmaf(bf2f((u16)(ww[q] >> 16)),     ga, be) + loadv(x, (long)e + 2 * q + 1, f32), 0.f);
    }
    if (f32) {
        float4* op = (float4*)((float*)outp + e);
        op[0] = make_float4(v[0], v[1], v[2], v[3]);
        op[1] = make_float4(v[4], v[5], v[6], v[7]);
    } else {
        uint4 o;
        o.x = (u32)f2bf(v[0]) | ((u32)f2bf(v[1]) << 16);
        o.y = (u32)f2bf(v[2]) | ((u32)f2bf(v[3]) << 16);
        o.z = (u32)f2bf(v[4]) | ((u32)f2bf(v[5]) << 16);
        o.w = (u32)f2bf(v[6]) | ((u32)f2bf(v[7]) << 16);
        ((uint4*)outp)[i] = o;
    }
}

extern "C" void kernel_launch(void* const* d_in, const int* in_sizes, int n_in,
                              void* d_out, int out_size, void* d_ws, size_t ws_size,
                              hipStream_t stream) {
    const void* x     = d_in[0];
    const void* w_tm1 = d_in[1];
    const void* b_tm1 = d_in[2];
    const void* w_tr1 = d_in[3];
    const void* b_tr1 = d_in[4];
    const void* w_dc1 = d_in[5];
    const void* g1    = d_in[6];
    const void* be1   = d_in[7];
    const void* w_tm2 = d_in[8];
    const void* b_tm2 = d_in[9];
    const void* w_tr2 = d_in[10];
    const void* b_tr2 = d_in[11];
    const void* w_dc2 = d_in[12];
    const void* g2    = d_in[13];
    const void* be2   = d_in[14];

    char* wsb = (char*)d_ws;
    u16*   xT    = (u16*)wsb;                                   // 8,388,608 B (alias out1)
    u16*   raw   = (u16*)(wsb + 8388608);                       // 8,388,608 B
    u16*   wTg   = (u16*)(wsb + 16777216);                      // 1,179,648 B
    float* tmtr  = (float*)(wsb + 16777216 + 1179648);          //   393,216 B
    float* stats = (float*)(wsb + 16777216 + 1179648 + 393216); //     1,024 B
    u32*   flag  = (u32*)(wsb + 16777216 + 1179648 + 393216 + 1024);   // 16 B
    u16*   wT6   = (u16*)(wsb + 16777216 + 1179648 + 393216 + 1024 + 16); // 73,728 B
    u16*   out1  = xT;

    k_probe<<<1, 256, 0, stream>>>((const u32*)x, flag);

    // ---- round 1 ----
    k_to_nhwc <<<256, 256, 0, stream>>>(x, flag, xT);
    k_prep_w  <<<1152, 256, 0, stream>>>(w_dc1, flag, wTg, stats);
    k_prep_w6 <<<144, 256, 0, stream>>>(w_tm1, w_tr1, flag, wT6);
    k_conv6   <<<256, 512, 0, stream>>>(xT, wT6, b_tm1, b_tr1, flag, tmtr);
    k_deform  <<<512, 512, 0, stream>>>(xT, tmtr, wTg, raw, stats);
    k_gn_relu <<<256, 256, 0, stream>>>(raw, stats, g1, be1, flag, out1);
    // ---- round 2 ----
    k_prep_w  <<<1152, 256, 0, stream>>>(w_dc2, flag, wTg, stats);
    k_prep_w6 <<<144, 256, 0, stream>>>(w_tm2, w_tr2, flag, wT6);
    k_conv6   <<<256, 512, 0, stream>>>(out1, wT6, b_tm2, b_tr2, flag, tmtr);
    k_deform  <<<512, 512, 0, stream>>>(out1, tmtr, wTg, raw, stats);
    k_gn_final<<<2048, 256, 0, stream>>>(raw, stats, g2, be2, x, flag, d_out);
}

// Round 9
// 351.650 us; speedup vs baseline: 1.0477x; 1.0477x over previous
//
#include <hip/hip_runtime.h>

// NHWC MFMA pipeline v5 = round-7 deform (measured best) + fused GN stats +
// coalesced prep/transpose helpers. k_gn_stats launches eliminated.
// ws: xT/out1 (NHWC bf16, alias) 8 MB | raw (NCHW bf16) 8 MB | wTg 1.18 MB |
//     tmtr 0.39 MB | stats 1 KB | flag 16 B | wT6 73,728 B  (~17.6 MiB)

typedef unsigned int u32;
typedef unsigned short u16;
typedef __attribute__((ext_vector_type(8))) short bf16x8;
typedef __attribute__((ext_vector_type(4))) float floatx4;

#define HW 4096
#define CHW 1048576

static __device__ __forceinline__ float bf2f(u16 u) {
    union { u32 i; float f; } c; c.i = ((u32)u) << 16; return c.f;
}
static __device__ __forceinline__ u16 f2bf(float f) {
    union { float f; u32 i; } c; c.f = f;
    u32 x = c.i;
    return (u16)((x + 0x7FFFu + ((x >> 16) & 1u)) >> 16);   // RNE
}
static __device__ __forceinline__ float loadv(const void* p, long i, int f32) {
    return f32 ? ((const float*)p)[i] : bf2f(((const u16*)p)[i]);
}

__global__ __launch_bounds__(256) void k_probe(const u32* __restrict__ xw,
                                               u32* __restrict__ flag) {
    __shared__ int cnt;
    if (threadIdx.x == 0) cnt = 0;
    __syncthreads();
    union { u32 i; float f; } c;
    c.i = xw[threadIdx.x * 997];
    float a = fabsf(c.f);
    if (a > 1e-8f && a < 1e4f) atomicAdd(&cnt, 1);
    __syncthreads();
    if (threadIdx.x == 0) { flag[0] = (cnt >= 128) ? 1u : 0u; flag[1] = 0u; }
}

// ---------------------------------------------------------------------------
// NCHW (flag dtype) -> NHWC bf16 via LDS transpose; coalesced both sides.
// ---------------------------------------------------------------------------
__global__ __launch_bounds__(256) void k_to_nhwc(const void* __restrict__ src,
                                                 const u32* __restrict__ flag,
                                                 u16* __restrict__ dst) {
    __shared__ u16 T[64 * 258];
    const int f32 = (int)flag[0];
    const int bid = blockIdx.x;      // n*64 + h
    const int n = bid >> 6, h = bid & 63;
    const int tid = threadIdx.x;
    const long sb = (long)n * CHW + (h << 6);
    for (int it = 0; it < 64; ++it) {
        int e = it * 256 + tid;
        int c = e >> 6, w = e & 63;
        T[w * 258 + c] = f2bf(loadv(src, sb + (long)c * HW + w, f32));
    }
    __syncthreads();
    const int w = tid >> 2, cq = tid & 3;
    const u32* Tr = (const u32*)T;
    u16* ob = dst + (long)n * CHW + (long)((h << 6) + w) * 256 + cq * 64;
    #pragma unroll
    for (int s = 0; s < 8; ++s) {
        uint4 o;
        o.x = Tr[129 * w + 32 * cq + 4 * s + 0];
        o.y = Tr[129 * w + 32 * cq + 4 * s + 1];
        o.z = Tr[129 * w + 32 * cq + 4 * s + 2];
        o.w = Tr[129 * w + 32 * cq + 4 * s + 3];
        *(uint4*)&ob[s * 8] = o;
    }
}

// ---------------------------------------------------------------------------
// Pack deform weights (dest-indexed, coalesced u32 stores):
// wTg[(q*256 + o)*32 + c%32] <- w_dc[o][c][k],  q = k*8 + c/32.
// Block 0 zeroes the GN-stats accumulator (runs before k_deform).
// ---------------------------------------------------------------------------
__global__ __launch_bounds__(256) void k_prep_w(const void* __restrict__ wdc,
                                                const u32* __restrict__ flag,
                                                u16* __restrict__ wTg,
                                                float* __restrict__ stats) {
    if (blockIdx.x == 0) stats[threadIdx.x] = 0.f;   // 256 floats
    const int f32 = (int)flag[0];
    int idx2 = blockIdx.x * 256 + threadIdx.x;       // 1152 blocks -> 294912
    int cp = idx2 & 15;
    int o  = (idx2 >> 4) & 255;
    int q  = idx2 >> 12;
    int k  = q >> 3;
    int c0 = ((q & 7) << 5) + (cp << 1);
    long s0 = (long)o * 2304 + c0 * 9 + k;
    u16 w0 = f2bf(loadv(wdc, s0, f32));
    u16 w1 = f2bf(loadv(wdc, s0 + 9, f32));
    ((u32*)wTg)[idx2] = (u32)w0 | ((u32)w1 << 16);
}

// ---------------------------------------------------------------------------
// Pack offset-conv weights: [oc][c][k] -> wT6[q][o(16)][c%32]
// ---------------------------------------------------------------------------
__global__ __launch_bounds__(256) void k_prep_w6(const void* __restrict__ w_tm,
                                                 const void* __restrict__ w_tr,
                                                 const u32* __restrict__ flag,
                                                 u16* __restrict__ wT6) {
    const int f32 = (int)flag[0];
    int i = blockIdx.x * 256 + threadIdx.x;   // 144 blocks = 36864
    int q  = i >> 9;
    int o  = (i >> 5) & 15;
    int cc = i & 31;
    int k  = q >> 3;
    int c  = ((q & 7) << 5) + cc;
    float v = 0.f;
    if (o < 4)      v = loadv(w_tm, (long)o * 2304 + c * 9 + k, f32);
    else if (o < 6) v = loadv(w_tr, (long)(o - 4) * 2304 + c * 9 + k, f32);
    wT6[i] = f2bf(v);
}

// ---------------------------------------------------------------------------
// MFMA offset conv: D[6][64] per (n,h) row.
// ---------------------------------------------------------------------------
__global__ __launch_bounds__(512) void k_conv6(
    const u16* __restrict__ srcT, const u16* __restrict__ wT6,
    const void* __restrict__ b_tm, const void* __restrict__ b_tr,
    const u32* __restrict__ flag,
    float* __restrict__ tmtr)
{
    __shared__ float red[8][64][17];
    const int tid = threadIdx.x;
    const int bid = blockIdx.x;
    const int n = bid >> 6, h = bid & 63;
    const int wv = tid >> 6;
    const int lane = tid & 63;
    const int quad = lane >> 4;
    const int l16 = lane & 15;
    const u16* sp = srcT + (long)n * CHW;

    floatx4 acc[4];
    #pragma unroll
    for (int j4 = 0; j4 < 4; ++j4) acc[j4] = (floatx4){0.f, 0.f, 0.f, 0.f};

    for (int qi = 0; qi < 9; ++qi) {
        const int q = wv * 9 + qi;
        const int k = q >> 3, cb = q & 7;
        const int ky = k / 3, kx = k % 3;
        const int row = h + ky - 1;
        const bool rv = (row >= 0) && (row < 64);
        bf16x8 av = *(const bf16x8*)&wT6[(((q << 4) + l16) << 5) + (quad << 3)];
        #pragma unroll
        for (int j4 = 0; j4 < 4; ++j4) {
            int w = (j4 << 4) + l16;
            int px = w + kx - 1;
            bf16x8 bv = {0, 0, 0, 0, 0, 0, 0, 0};
            if (rv && px >= 0 && px < 64)
                bv = *(const bf16x8*)&sp[(((long)(row << 6) + px) << 8) + (cb << 5) + (quad << 3)];
            acc[j4] = __builtin_amdgcn_mfma_f32_16x16x32_bf16(av, bv, acc[j4], 0, 0, 0);
        }
    }
    #pragma unroll
    for (int j4 = 0; j4 < 4; ++j4)
        #pragma unroll
        for (int r = 0; r < 4; ++r)
            red[wv][lane][(j4 << 2) + r] = acc[j4][r];
    __syncthreads();
    if (tid < 384) {
        const int o = tid >> 6, w = tid & 63;
        const int ln = ((o >> 2) << 4) + (w & 15);
        const int slot = ((w >> 4) << 2) + (o & 3);
        float s = 0.f;
        #pragma unroll
        for (int v = 0; v < 8; ++v) s += red[v][ln][slot];
        const int f32 = (int)flag[0];
        float bias = (o < 4) ? loadv(b_tm, o, f32) : loadv(b_tr, o - 4, f32);
        tmtr[((long)n * 6 + o) * HW + (h << 6) + w] = s + bias;
    }
}

// ---------------------------------------------------------------------------
// MFMA deform conv (round-7 structure, measured 59.6 µs) + fused GN stats.
// Grid 512: block = (n, h, px-half); 8 waves; each wave 32o x 32px.
// A-frags direct from L2-resident wTg; LDS only for sampled S (dbuf) + geom.
// ---------------------------------------------------------------------------
__global__ __launch_bounds__(512, 4) void k_deform(
    const u16* __restrict__ srcT, const float* __restrict__ tmtr,
    const u16* __restrict__ wTg, u16* __restrict__ raw,
    float* __restrict__ stats)
{
    __shared__ __align__(16) short Sl[2][32 * 40];   // 5120 B
    __shared__ int   g_y0[288];
    __shared__ int   g_x0[288];
    __shared__ float g_wy[288];
    __shared__ float g_wx[288];

    const int tid = threadIdx.x;
    const int bid = blockIdx.x;                 // n*128 + h*2 + half
    const int n = bid >> 7, h = (bid >> 1) & 63, half = bid & 1;
    const float* tb = tmtr + (long)n * 6 * HW + (h << 6) + (half << 5);

    for (int i = tid; i < 288; i += 512) {      // geometry for 9k x 32px
        int k = i >> 5, ww2 = i & 31;
        float m00 = tb[ww2],          m01 = tb[HW + ww2];
        float m10 = tb[2 * HW + ww2], m11 = tb[3 * HW + ww2];
        float tr0 = tb[4 * HW + ww2], tr1 = tb[5 * HW + ww2];
        float ry = (float)(k / 3) - 1.f;
        float rx = (float)(k % 3) - 1.f;
        float dy = m00 * ry + m01 * rx - ry + tr0;
        float dx = m10 * ry + m11 * rx - rx + tr1;
        float py = (float)h + ry + dy;
        float px = (float)((half << 5) + ww2) + rx + dx;
        float y0f = floorf(py), x0f = floorf(px);
        g_y0[i] = (int)y0f; g_x0[i] = (int)x0f;
        g_wy[i] = py - y0f; g_wx[i] = px - x0f;
    }
    __syncthreads();

    const long nbase = (long)n * CHW;
    const u16* sp = srcT + nbase;
    const int sw  = tid >> 4;      // px 0..31
    const int scq = tid & 15;      // channel pair
    const int lane = tid & 63;
    const int quad = lane >> 4;
    const int l16  = lane & 15;
    const int o0   = (tid >> 6) << 5;

    floatx4 acc[2][2];
    #pragma unroll
    for (int i = 0; i < 2; ++i)
        #pragma unroll
        for (int j = 0; j < 2; ++j)
            acc[i][j] = (floatx4){0.f, 0.f, 0.f, 0.f};

    int a00 = 0, a01 = 0, a10 = 0, a11 = 0;
    float cw00 = 0.f, cw01 = 0.f, cw10 = 0.f, cw11 = 0.f;
    int cur_k = -1;
    u32 s00 = 0, s01 = 0, s10 = 0, s11 = 0;
    bf16x8 wa = {0,0,0,0,0,0,0,0}, wb = {0,0,0,0,0,0,0,0};

    auto issue = [&](int q) {
        const int k = q >> 3;
        if (k != cur_k) {
            cur_k = k;
            int gi = (k << 5) + sw;
            int y0 = g_y0[gi], x0 = g_x0[gi];
            float wy1 = g_wy[gi], wx1 = g_wx[gi];
            float wy0 = 1.f - wy1, wx0 = 1.f - wx1;
            bool yv0 = (y0 >= 0) && (y0 < 64);
            bool yv1 = (y0 >= -1) && (y0 < 63);
            bool xv0 = (x0 >= 0) && (x0 < 64);
            bool xv1 = (x0 >= -1) && (x0 < 63);
            int yc0 = min(max(y0, 0), 63),     yc1 = min(max(y0 + 1, 0), 63);
            int xc0 = min(max(x0, 0), 63),     xc1 = min(max(x0 + 1, 0), 63);
            a00 = yc0 * 64 + xc0; a01 = yc0 * 64 + xc1;
            a10 = yc1 * 64 + xc0; a11 = yc1 * 64 + xc1;
            cw00 = (yv0 && xv0) ? wy0 * wx0 : 0.f;
            cw01 = (yv0 && xv1) ? wy0 * wx1 : 0.f;
            cw10 = (yv1 && xv0) ? wy1 * wx0 : 0.f;
            cw11 = (yv1 && xv1) ? wy1 * wx1 : 0.f;
        }
        const int cc = ((q & 7) << 5) + (scq << 1);   // 2 channels
        s00 = *(const u32*)&sp[(long)a00 * 256 + cc];
        s01 = *(const u32*)&sp[(long)a01 * 256 + cc];
        s10 = *(const u32*)&sp[(long)a10 * 256 + cc];
        s11 = *(const u32*)&sp[(long)a11 * 256 + cc];
        const u16* wp = wTg + (((size_t)q * 256 + o0 + l16) << 5) + (quad << 3);
        wa = *(const bf16x8*)wp;
        wb = *(const bf16x8*)(wp + (16 << 5));
    };
    auto publish = [&](int b) {
        float va = fmaf(cw00, bf2f((u16)s00),
                   fmaf(cw01, bf2f((u16)s01),
                   fmaf(cw10, bf2f((u16)s10), cw11 * bf2f((u16)s11))));
        float vb = fmaf(cw00, bf2f((u16)(s00 >> 16)),
                   fmaf(cw01, bf2f((u16)(s01 >> 16)),
                   fmaf(cw10, bf2f((u16)(s10 >> 16)), cw11 * bf2f((u16)(s11 >> 16)))));
        *(u32*)&Sl[b][sw * 40 + (scq << 1)] = (u32)f2bf(va) | ((u32)f2bf(vb) << 16);
    };

    issue(0);
    publish(0);
    bf16x8 A0 = wa, A1 = wb;
    __syncthreads();

    for (int q = 0; q < 72; ++q) {
        if (q + 1 < 72) issue(q + 1);
        {
            const int b = q & 1;
            #pragma unroll
            for (int j = 0; j < 2; ++j) {
                bf16x8 bv = *(const bf16x8*)&Sl[b][((j << 4) + l16) * 40 + (quad << 3)];
                acc[0][j] = __builtin_amdgcn_mfma_f32_16x16x32_bf16(A0, bv, acc[0][j], 0, 0, 0);
                acc[1][j] = __builtin_amdgcn_mfma_f32_16x16x32_bf16(A1, bv, acc[1][j], 0, 0, 0);
            }
        }
        if (q + 1 < 72) { publish((q + 1) & 1); A0 = wa; A1 = wb; }
        __syncthreads();
    }

    // fused GN statistics: two 32-lane reductions per i, then atomicAdd.
    // lanes 0..31 hold o_within 0..7 (group offset 0); lanes 32..63 -> offset 1.
    #pragma unroll
    for (int i = 0; i < 2; ++i) {
        float s1 = 0.f, s2 = 0.f;
        #pragma unroll
        for (int j = 0; j < 2; ++j)
            #pragma unroll
            for (int r = 0; r < 4; ++r) {
                float v = acc[i][j][r];
                s1 += v; s2 += v * v;
            }
        #pragma unroll
        for (int off = 1; off <= 16; off <<= 1) {
            s1 += __shfl_xor(s1, off, 64);
            s2 += __shfl_xor(s2, off, 64);
        }
        if ((lane & 31) == 0) {
            int g = (o0 >> 3) + 2 * i + (lane >> 5);
            atomicAdd(&stats[(n * 32 + g) * 2], s1);
            atomicAdd(&stats[(n * 32 + g) * 2 + 1], s2);
        }
    }

    // epilogue: o = o0 + i*16 + quad*4 + r, w = half*32 + j*16 + l16
    #pragma unroll
    for (int i = 0; i < 2; ++i)
        #pragma unroll
        for (int j = 0; j < 2; ++j)
            #pragma unroll
            for (int r = 0; r < 4; ++r) {
                int o = o0 + i * 16 + quad * 4 + r;
                raw[nbase + ((long)o << 12) + (h << 6) + (half << 5) + (j << 4) + l16]
                    = f2bf(acc[i][j][r]);
            }
}

// ---------------------------------------------------------------------------
// GN + relu; raw (NCHW bf16) -> out1 (NHWC bf16) via LDS transpose.
// stats[] holds raw (sum, sumsq).
// ---------------------------------------------------------------------------
__global__ __launch_bounds__(256) void k_gn_relu(
    const u16* __restrict__ raw, const float* __restrict__ stats,
    const void* __restrict__ gamma, const void* __restrict__ beta,
    const u32* __restrict__ flag,
    u16* __restrict__ out1)
{
    __shared__ u16 T[64 * 258];
    const int f32 = (int)flag[0];
    const int bid = blockIdx.x;
    const int n = bid >> 6, h = bid & 63;
    const int tid = threadIdx.x;
    const u16* rb = raw + (long)n * CHW + (h << 6);
    for (int it = 0; it < 64; ++it) {
        int e = it * 256 + tid;
        int c = e >> 6, w = e & 63;
        int ng = n * 32 + (c >> 3);
        float mean = stats[ng * 2] * (1.f / 32768.f);
        float var  = stats[ng * 2 + 1] * (1.f / 32768.f) - mean * mean;
        float rstd = rsqrtf(var + 1e-5f);
        float ga = loadv(gamma, c, f32) * rstd;
        float be = loadv(beta, c, f32) - mean * ga;
        float v = fmaxf(fmaf(bf2f(rb[(long)c * HW + w]), ga, be), 0.f);
        T[w * 258 + c] = f2bf(v);
    }
    __syncthreads();
    const int w = tid >> 2, cq = tid & 3;
    const u32* Tr = (const u32*)T;
    u16* ob = out1 + (long)n * CHW + (long)((h << 6) + w) * 256 + cq * 64;
    #pragma unroll
    for (int s = 0; s < 8; ++s) {
        uint4 o;
        o.x = Tr[129 * w + 32 * cq + 4 * s + 0];
        o.y = Tr[129 * w + 32 * cq + 4 * s + 1];
        o.z = Tr[129 * w + 32 * cq + 4 * s + 2];
        o.w = Tr[129 * w + 32 * cq + 4 * s + 3];
        *(uint4*)&ob[s * 8] = o;
    }
}

// ---------------------------------------------------------------------------
__global__ __launch_bounds__(256) void k_gn_final(
    const u16* __restrict__ raw, const float* __restrict__ stats,
    const void* __restrict__ gamma, const void* __restrict__ beta,
    const void* __restrict__ x, const u32* __restrict__ flag,
    void* __restrict__ outp)
{
    const int f32 = (int)flag[0];
    const int i = blockIdx.x * 256 + threadIdx.x;
    const int e = i << 3;
    const int c = (e >> 12) & 255;
    const int ng = (e >> 20) * 32 + (c >> 3);
    float mean = stats[ng * 2] * (1.f / 32768.f);
    float var  = stats[ng * 2 + 1] * (1.f / 32768.f) - mean * mean;
    float rstd = rsqrtf(var + 1e-5f);
    float ga = loadv(gamma, c, f32) * rstd;
    float be = loadv(beta, c, f32) - mean * ga;
    uint4 p = ((const uint4*)raw)[i];
    u32 ww[4] = {p.x, p.y, p.z, p.w};
    float v[8];
    #pragma unroll
    for (int q = 0; q < 4; ++q) {
        v[2 * q + 0] = fmaxf(fmaf(bf2f((u16)(ww[q] & 0xFFFFu)), ga, be) + loadv(x, (long)e + 2 * q + 0, f32), 0.f);
        v[2 * q + 1] = fmaxf(fmaf(bf2f((u16)(ww[q] >> 16)),     ga, be) + loadv(x, (long)e + 2 * q + 1, f32), 0.f);
    }
    if (f32) {
        float4* op = (float4*)((float*)outp + e);
        op[0] = make_float4(v[0], v[1], v[2], v[3]);
        op[1] = make_float4(v[4], v[5], v[6], v[7]);
    } else {
        uint4 o;
        o.x = (u32)f2bf(v[0]) | ((u32)f2bf(v[1]) << 16);
        o.y = (u32)f2bf(v[2]) | ((u32)f2bf(v[3]) << 16);
        o.z = (u32)f2bf(v[4]) | ((u32)f2bf(v[5]) << 16);
        o.w = (u32)f2bf(v[6]) | ((u32)f2bf(v[7]) << 16);
        ((uint4*)outp)[i] = o;
    }
}

extern "C" void kernel_launch(void* const* d_in, const int* in_sizes, int n_in,
                              void* d_out, int out_size, void* d_ws, size_t ws_size,
                              hipStream_t stream) {
    const void* x     = d_in[0];
    const void* w_tm1 = d_in[1];
    const void* b_tm1 = d_in[2];
    const void* w_tr1 = d_in[3];
    const void* b_tr1 = d_in[4];
    const void* w_dc1 = d_in[5];
    const void* g1    = d_in[6];
    const void* be1   = d_in[7];
    const void* w_tm2 = d_in[8];
    const void* b_tm2 = d_in[9];
    const void* w_tr2 = d_in[10];
    const void* b_tr2 = d_in[11];
    const void* w_dc2 = d_in[12];
    const void* g2    = d_in[13];
    const void* be2   = d_in[14];

    char* wsb = (char*)d_ws;
    u16*   xT    = (u16*)wsb;                                   // 8,388,608 B (alias out1)
    u16*   raw   = (u16*)(wsb + 8388608);                       // 8,388,608 B
    u16*   wTg   = (u16*)(wsb + 16777216);                      // 1,179,648 B
    float* tmtr  = (float*)(wsb + 16777216 + 1179648);          //   393,216 B
    float* stats = (float*)(wsb + 16777216 + 1179648 + 393216); //     1,024 B
    u32*   flag  = (u32*)(wsb + 16777216 + 1179648 + 393216 + 1024);   // 16 B
    u16*   wT6   = (u16*)(wsb + 16777216 + 1179648 + 393216 + 1024 + 16); // 73,728 B
    u16*   out1  = xT;

    k_probe<<<1, 256, 0, stream>>>((const u32*)x, flag);

    // ---- round 1 ----
    k_to_nhwc <<<256, 256, 0, stream>>>(x, flag, xT);
    k_prep_w  <<<1152, 256, 0, stream>>>(w_dc1, flag, wTg, stats);
    k_prep_w6 <<<144, 256, 0, stream>>>(w_tm1, w_tr1, flag, wT6);
    k_conv6   <<<256, 512, 0, stream>>>(xT, wT6, b_tm1, b_tr1, flag, tmtr);
    k_deform  <<<512, 512, 0, stream>>>(xT, tmtr, wTg, raw, stats);
    k_gn_relu <<<256, 256, 0, stream>>>(raw, stats, g1, be1, flag, out1);
    // ---- round 2 ----
    k_prep_w  <<<1152, 256, 0, stream>>>(w_dc2, flag, wTg, stats);
    k_prep_w6 <<<144, 256, 0, stream>>>(w_tm2, w_tr2, flag, wT6);
    k_conv6   <<<256, 512, 0, stream>>>(out1, wT6, b_tm2, b_tr2, flag, tmtr);
    k_deform  <<<512, 512, 0, stream>>>(out1, tmtr, wTg, raw, stats);
    k_gn_final<<<2048, 256, 0, stream>>>(raw, stats, g2, be2, x, flag, d_out);
}

// Round 10
// 283.992 us; speedup vs baseline: 1.2973x; 1.2382x over previous
//
#include <hip/hip_runtime.h>

// v6: 6 dispatches. Mega-deform (offset-conv fused in, per-block GN partials,
// NO atomics), single prep kernel for both rounds, GN kernels reduce partials.
// ws (19,415,056 B): xT/out1 8MB | raw 8MB | wTg1 1.18MB | wTg2 1.18MB |
//   wT61 72KB | wT62 72KB | pstats 128KB | flag 16B

typedef unsigned int u32;
typedef unsigned short u16;
typedef __attribute__((ext_vector_type(8))) short bf16x8;
typedef __attribute__((ext_vector_type(4))) float floatx4;

#define HW 4096
#define CHW 1048576

static __device__ __forceinline__ float bf2f(u16 u) {
    union { u32 i; float f; } c; c.i = ((u32)u) << 16; return c.f;
}
static __device__ __forceinline__ u16 f2bf(float f) {
    union { float f; u32 i; } c; c.f = f;
    u32 x = c.i;
    return (u16)((x + 0x7FFFu + ((x >> 16) & 1u)) >> 16);   // RNE
}
static __device__ __forceinline__ float loadv(const void* p, long i, int f32) {
    return f32 ? ((const float*)p)[i] : bf2f(((const u16*)p)[i]);
}

__global__ __launch_bounds__(256) void k_probe(const u32* __restrict__ xw,
                                               u32* __restrict__ flag) {
    __shared__ int cnt;
    if (threadIdx.x == 0) cnt = 0;
    __syncthreads();
    union { u32 i; float f; } c;
    c.i = xw[threadIdx.x * 997];
    float a = fabsf(c.f);
    if (a > 1e-8f && a < 1e4f) atomicAdd(&cnt, 1);
    __syncthreads();
    if (threadIdx.x == 0) { flag[0] = (cnt >= 128) ? 1u : 0u; flag[1] = 0u; }
}

// ---------------------------------------------------------------------------
// One prep kernel: blocks [0,256) NCHW->NHWC transpose; [256,1408) wTg1;
// [1408,2560) wTg2; [2560,2704) wT61; [2704,2848) wT62.
// ---------------------------------------------------------------------------
__global__ __launch_bounds__(256) void k_prep_all(
    const void* __restrict__ x,
    const void* __restrict__ wdc1, const void* __restrict__ wdc2,
    const void* __restrict__ wtm1, const void* __restrict__ wtr1,
    const void* __restrict__ wtm2, const void* __restrict__ wtr2,
    const u32* __restrict__ flag,
    u16* __restrict__ xT, u16* __restrict__ wTg1, u16* __restrict__ wTg2,
    u16* __restrict__ wT61, u16* __restrict__ wT62)
{
    __shared__ u16 T[64 * 258];
    const int f32 = (int)flag[0];
    const int b = blockIdx.x;
    const int tid = threadIdx.x;

    if (b < 256) {                       // ---- NCHW -> NHWC (LDS transpose)
        const int n = b >> 6, h = b & 63;
        const long sb = (long)n * CHW + (h << 6);
        for (int it = 0; it < 64; ++it) {
            int e = it * 256 + tid;
            int c = e >> 6, w = e & 63;
            T[w * 258 + c] = f2bf(loadv(x, sb + (long)c * HW + w, f32));
        }
        __syncthreads();
        const int w = tid >> 2, cq = tid & 3;
        const u32* Tr = (const u32*)T;
        u16* ob = xT + (long)n * CHW + (long)((h << 6) + w) * 256 + cq * 64;
        #pragma unroll
        for (int s = 0; s < 8; ++s) {
            uint4 o;
            o.x = Tr[129 * w + 32 * cq + 4 * s + 0];
            o.y = Tr[129 * w + 32 * cq + 4 * s + 1];
            o.z = Tr[129 * w + 32 * cq + 4 * s + 2];
            o.w = Tr[129 * w + 32 * cq + 4 * s + 3];
            *(uint4*)&ob[s * 8] = o;
        }
    } else if (b < 2560) {               // ---- deform weights (both rounds)
        const int r2 = (b >= 1408);
        const void* wdc = r2 ? wdc2 : wdc1;
        u16* wTg = r2 ? wTg2 : wTg1;
        int idx2 = (b - (r2 ? 1408 : 256)) * 256 + tid;   // 0..294911
        int cp = idx2 & 15;
        int o  = (idx2 >> 4) & 255;
        int q  = idx2 >> 12;
        int k  = q >> 3;
        int c0 = ((q & 7) << 5) + (cp << 1);
        long s0 = (long)o * 2304 + c0 * 9 + k;
        u16 w0 = f2bf(loadv(wdc, s0, f32));
        u16 w1 = f2bf(loadv(wdc, s0 + 9, f32));
        ((u32*)wTg)[idx2] = (u32)w0 | ((u32)w1 << 16);
    } else {                             // ---- offset-conv weights
        const int r2 = (b >= 2704);
        const void* wtm = r2 ? wtm2 : wtm1;
        const void* wtr = r2 ? wtr2 : wtr1;
        u16* wT6 = r2 ? wT62 : wT61;
        int i = (b - (r2 ? 2704 : 2560)) * 256 + tid;     // 0..36863
        int q  = i >> 9;
        int o  = (i >> 5) & 15;
        int cc = i & 31;
        int k  = q >> 3;
        int c  = ((q & 7) << 5) + cc;
        float v = 0.f;
        if (o < 4)      v = loadv(wtm, (long)o * 2304 + c * 9 + k, f32);
        else if (o < 6) v = loadv(wtr, (long)(o - 4) * 2304 + c * 9 + k, f32);
        wT6[i] = f2bf(v);
    }
}

// ---------------------------------------------------------------------------
// Mega deform: per (n,h,half) block [512 total, 512 thr = 8 waves]:
//   Stage A: offset conv (MFMA) -> tmtr slice in LDS
//   Stage B: build_offset geometry
//   Stage C: round-7 K-loop (72 chunks, A-frags direct from L2 wTg)
//   Stage D: GN partials -> pstats[bid][64] (plain stores, NO atomics)
//   Stage E: raw (NCHW bf16) stores
// ---------------------------------------------------------------------------
__global__ __launch_bounds__(512, 4) void k_deform(
    const u16* __restrict__ srcT, const u16* __restrict__ wTg,
    const u16* __restrict__ wT6,
    const void* __restrict__ b_tm, const void* __restrict__ b_tr,
    const u32* __restrict__ flag,
    u16* __restrict__ raw, float* __restrict__ pstats)
{
    __shared__ float red[8][32][17];                 // 17408 B (stage A)
    __shared__ float tl[6 * 32];                     //   768 B
    __shared__ __align__(16) short Sl[2][32 * 40];   //  5120 B
    __shared__ int   g_y0[288];
    __shared__ int   g_x0[288];
    __shared__ float g_wy[288];
    __shared__ float g_wx[288];

    const int tid = threadIdx.x;
    const int bid = blockIdx.x;                 // n*128 + h*2 + half
    const int n = bid >> 7, h = (bid >> 1) & 63, half = bid & 1;
    const int wb = half << 5;
    const int lane = tid & 63;
    const int quad = lane >> 4;
    const int l16  = lane & 15;
    const int wv   = tid >> 6;
    const long nbase = (long)n * CHW;
    const u16* sp = srcT + nbase;

    // ---- Stage A: offset conv, 6 out-ch x 32 px ----
    {
        floatx4 acc6[2];
        acc6[0] = (floatx4){0.f, 0.f, 0.f, 0.f};
        acc6[1] = (floatx4){0.f, 0.f, 0.f, 0.f};
        for (int qi = 0; qi < 9; ++qi) {
            const int q = wv * 9 + qi;
            const int k = q >> 3, cb = q & 7;
            const int ky = k / 3, kx = k % 3;
            const int row = h + ky - 1;
            const bool rv = (row >= 0) && (row < 64);
            bf16x8 av = *(const bf16x8*)&wT6[(((q << 4) + l16) << 5) + (quad << 3)];
            #pragma unroll
            for (int j = 0; j < 2; ++j) {
                int psrc = wb + (j << 4) + l16 + kx - 1;
                bf16x8 bv = {0, 0, 0, 0, 0, 0, 0, 0};
                if (rv && psrc >= 0 && psrc < 64)
                    bv = *(const bf16x8*)&sp[(((long)(row << 6) + psrc) << 8) + (cb << 5) + (quad << 3)];
                acc6[j] = __builtin_amdgcn_mfma_f32_16x16x32_bf16(av, bv, acc6[j], 0, 0, 0);
            }
        }
        #pragma unroll
        for (int j = 0; j < 2; ++j)
            #pragma unroll
            for (int r = 0; r < 4; ++r)
                red[wv][(j << 4) + l16][(quad << 2) + r] = acc6[j][r];
        __syncthreads();
        if (tid < 192) {
            const int o = tid >> 5, px = tid & 31;
            float s = 0.f;
            #pragma unroll
            for (int v = 0; v < 8; ++v) s += red[v][px][o];
            const int f32 = (int)flag[0];
            float bias = (o < 4) ? loadv(b_tm, o, f32) : loadv(b_tr, o - 4, f32);
            tl[o * 32 + px] = s + bias;
        }
        __syncthreads();
    }

    // ---- Stage B: geometry for 9 taps x 32 px ----
    for (int i = tid; i < 288; i += 512) {
        int k = i >> 5, ww2 = i & 31;
        float m00 = tl[ww2],       m01 = tl[32 + ww2];
        float m10 = tl[64 + ww2],  m11 = tl[96 + ww2];
        float tr0 = tl[128 + ww2], tr1 = tl[160 + ww2];
        float ry = (float)(k / 3) - 1.f;
        float rx = (float)(k % 3) - 1.f;
        float dy = m00 * ry + m01 * rx - ry + tr0;
        float dx = m10 * ry + m11 * rx - rx + tr1;
        float py = (float)h + ry + dy;
        float px = (float)(wb + ww2) + rx + dx;
        float y0f = floorf(py), x0f = floorf(px);
        g_y0[i] = (int)y0f; g_x0[i] = (int)x0f;
        g_wy[i] = py - y0f; g_wx[i] = px - x0f;
    }
    __syncthreads();

    // ---- Stage C: main K-loop (round-7 structure) ----
    const int sw  = tid >> 4;      // px 0..31
    const int scq = tid & 15;      // channel pair
    const int o0  = wv << 5;

    floatx4 acc[2][2];
    #pragma unroll
    for (int i = 0; i < 2; ++i)
        #pragma unroll
        for (int j = 0; j < 2; ++j)
            acc[i][j] = (floatx4){0.f, 0.f, 0.f, 0.f};

    int a00 = 0, a01 = 0, a10 = 0, a11 = 0;
    float cw00 = 0.f, cw01 = 0.f, cw10 = 0.f, cw11 = 0.f;
    int cur_k = -1;
    u32 s00 = 0, s01 = 0, s10 = 0, s11 = 0;
    bf16x8 wa = {0,0,0,0,0,0,0,0}, wbv = {0,0,0,0,0,0,0,0};

    auto issue = [&](int q) {
        const int k = q >> 3;
        if (k != cur_k) {
            cur_k = k;
            int gi = (k << 5) + sw;
            int y0 = g_y0[gi], x0 = g_x0[gi];
            float wy1 = g_wy[gi], wx1 = g_wx[gi];
            float wy0 = 1.f - wy1, wx0 = 1.f - wx1;
            bool yv0 = (y0 >= 0) && (y0 < 64);
            bool yv1 = (y0 >= -1) && (y0 < 63);
            bool xv0 = (x0 >= 0) && (x0 < 64);
            bool xv1 = (x0 >= -1) && (x0 < 63);
            int yc0 = min(max(y0, 0), 63),     yc1 = min(max(y0 + 1, 0), 63);
            int xc0 = min(max(x0, 0), 63),     xc1 = min(max(x0 + 1, 0), 63);
            a00 = yc0 * 64 + xc0; a01 = yc0 * 64 + xc1;
            a10 = yc1 * 64 + xc0; a11 = yc1 * 64 + xc1;
            cw00 = (yv0 && xv0) ? wy0 * wx0 : 0.f;
            cw01 = (yv0 && xv1) ? wy0 * wx1 : 0.f;
            cw10 = (yv1 && xv0) ? wy1 * wx0 : 0.f;
            cw11 = (yv1 && xv1) ? wy1 * wx1 : 0.f;
        }
        const int cc = ((q & 7) << 5) + (scq << 1);   // 2 channels
        s00 = *(const u32*)&sp[(long)a00 * 256 + cc];
        s01 = *(const u32*)&sp[(long)a01 * 256 + cc];
        s10 = *(const u32*)&sp[(long)a10 * 256 + cc];
        s11 = *(const u32*)&sp[(long)a11 * 256 + cc];
        const u16* wp = wTg + (((size_t)q * 256 + o0 + l16) << 5) + (quad << 3);
        wa  = *(const bf16x8*)wp;
        wbv = *(const bf16x8*)(wp + (16 << 5));
    };
    auto publish = [&](int b) {
        float va = fmaf(cw00, bf2f((u16)s00),
                   fmaf(cw01, bf2f((u16)s01),
                   fmaf(cw10, bf2f((u16)s10), cw11 * bf2f((u16)s11))));
        float vb = fmaf(cw00, bf2f((u16)(s00 >> 16)),
                   fmaf(cw01, bf2f((u16)(s01 >> 16)),
                   fmaf(cw10, bf2f((u16)(s10 >> 16)), cw11 * bf2f((u16)(s11 >> 16)))));
        *(u32*)&Sl[b][sw * 40 + (scq << 1)] = (u32)f2bf(va) | ((u32)f2bf(vb) << 16);
    };

    issue(0);
    publish(0);
    bf16x8 A0 = wa, A1 = wbv;
    __syncthreads();

    for (int q = 0; q < 72; ++q) {
        if (q + 1 < 72) issue(q + 1);
        {
            const int b = q & 1;
            #pragma unroll
            for (int j = 0; j < 2; ++j) {
                bf16x8 bv = *(const bf16x8*)&Sl[b][((j << 4) + l16) * 40 + (quad << 3)];
                acc[0][j] = __builtin_amdgcn_mfma_f32_16x16x32_bf16(A0, bv, acc[0][j], 0, 0, 0);
                acc[1][j] = __builtin_amdgcn_mfma_f32_16x16x32_bf16(A1, bv, acc[1][j], 0, 0, 0);
            }
        }
        if (q + 1 < 72) { publish((q + 1) & 1); A0 = wa; A1 = wbv; }
        __syncthreads();
    }

    // ---- Stage D: GN partials (no atomics) ----
    #pragma unroll
    for (int i = 0; i < 2; ++i) {
        float s1 = 0.f, s2 = 0.f;
        #pragma unroll
        for (int j = 0; j < 2; ++j)
            #pragma unroll
            for (int r = 0; r < 4; ++r) {
                float v = acc[i][j][r];
                s1 += v; s2 += v * v;
            }
        #pragma unroll
        for (int off = 1; off <= 16; off <<= 1) {
            s1 += __shfl_xor(s1, off, 64);
            s2 += __shfl_xor(s2, off, 64);
        }
        if ((lane & 31) == 0) {
            int g = (o0 >> 3) + 2 * i + (lane >> 5);
            pstats[((long)bid << 6) + (g << 1)]     = s1;
            pstats[((long)bid << 6) + (g << 1) + 1] = s2;
        }
    }

    // ---- Stage E: raw stores ----
    #pragma unroll
    for (int i = 0; i < 2; ++i)
        #pragma unroll
        for (int j = 0; j < 2; ++j)
            #pragma unroll
            for (int r = 0; r < 4; ++r) {
                int o = o0 + i * 16 + quad * 4 + r;
                raw[nbase + ((long)o << 12) + (h << 6) + wb + (j << 4) + l16]
                    = f2bf(acc[i][j][r]);
            }
}

// ---------------------------------------------------------------------------
// GN + relu; reduces pstats (128 partials of this n), raw NCHW -> out1 NHWC.
// ---------------------------------------------------------------------------
__global__ __launch_bounds__(256) void k_gn_relu(
    const u16* __restrict__ raw, const float* __restrict__ pstats,
    const void* __restrict__ gamma, const void* __restrict__ beta,
    const u32* __restrict__ flag,
    u16* __restrict__ out1)
{
    __shared__ u16 T[64 * 258];
    __shared__ float sred[4][64];
    __shared__ float sl[64];
    const int f32 = (int)flag[0];
    const int bid = blockIdx.x;
    const int n = bid >> 6, h = bid & 63;
    const int tid = threadIdx.x;

    {   // reduce partials: value v over 128 blocks of this n
        const int v = tid & 63, part = tid >> 6;
        float a = 0.f;
        for (int j = part * 32; j < part * 32 + 32; ++j)
            a += pstats[(((long)n * 128 + j) << 6) + v];
        sred[part][v] = a;
        __syncthreads();
        if (tid < 64) sl[tid] = sred[0][tid] + sred[1][tid] + sred[2][tid] + sred[3][tid];
        __syncthreads();
    }

    const u16* rb = raw + (long)n * CHW + (h << 6);
    for (int it = 0; it < 64; ++it) {
        int e = it * 256 + tid;
        int c = e >> 6, w = e & 63;
        int g = c >> 3;
        float mean = sl[g * 2] * (1.f / 32768.f);
        float var  = sl[g * 2 + 1] * (1.f / 32768.f) - mean * mean;
        float rstd = rsqrtf(var + 1e-5f);
        float ga = loadv(gamma, c, f32) * rstd;
        float be = loadv(beta, c, f32) - mean * ga;
        float v = fmaxf(fmaf(bf2f(rb[(long)c * HW + w]), ga, be), 0.f);
        T[w * 258 + c] = f2bf(v);
    }
    __syncthreads();
    const int w = tid >> 2, cq = tid & 3;
    const u32* Tr = (const u32*)T;
    u16* ob = out1 + (long)n * CHW + (long)((h << 6) + w) * 256 + cq * 64;
    #pragma unroll
    for (int s = 0; s < 8; ++s) {
        uint4 o;
        o.x = Tr[129 * w + 32 * cq + 4 * s + 0];
        o.y = Tr[129 * w + 32 * cq + 4 * s + 1];
        o.z = Tr[129 * w + 32 * cq + 4 * s + 2];
        o.w = Tr[129 * w + 32 * cq + 4 * s + 3];
        *(uint4*)&ob[s * 8] = o;
    }
}

// ---------------------------------------------------------------------------
// Final GN + residual + relu.  Each block covers one (n, group): reduce the
// 128 partials for that group, then elementwise.
// ---------------------------------------------------------------------------
__global__ __launch_bounds__(256) void k_gn_final(
    const u16* __restrict__ raw, const float* __restrict__ pstats,
    const void* __restrict__ gamma, const void* __restrict__ beta,
    const void* __restrict__ x, const u32* __restrict__ flag,
    void* __restrict__ outp)
{
    __shared__ float rr[256];
    const int f32 = (int)flag[0];
    const int tid = threadIdx.x;
    const long e0 = ((long)blockIdx.x) << 11;       // block-uniform
    const int n = (int)(e0 >> 20);
    const int c0 = (int)((e0 >> 12) & 255);
    const int g = c0 >> 3;

    {   // reduce 128 partials: rr[0..127] s1, rr[128..255] s2
        int j = tid & 127, sv = tid >> 7;
        rr[tid] = pstats[(((long)n * 128 + j) << 6) + (g << 1) + sv];
        __syncthreads();
        #pragma unroll
        for (int s = 64; s >= 1; s >>= 1) {
            if ((tid & 127) < s) rr[tid] += rr[tid + s];
            __syncthreads();
        }
    }
    float mean = rr[0] * (1.f / 32768.f);
    float var  = rr[128] * (1.f / 32768.f) - mean * mean;
    float rstd = rsqrtf(var + 1e-5f);

    const long i = blockIdx.x * 256 + tid;
    const long e = i << 3;
    const int c = (int)((e >> 12) & 255);
    float ga = loadv(gamma, c, f32) * rstd;
    float be = loadv(beta, c, f32) - mean * ga;
    uint4 p = ((const uint4*)raw)[i];
    u32 ww[4] = {p.x, p.y, p.z, p.w};
    float v[8];
    #pragma unroll
    for (int q = 0; q < 4; ++q) {
        v[2 * q + 0] = fmaxf(fmaf(bf2f((u16)(ww[q] & 0xFFFFu)), ga, be) + loadv(x, e + 2 * q + 0, f32), 0.f);
        v[2 * q + 1] = fmaxf(fmaf(bf2f((u16)(ww[q] >> 16)),     ga, be) + loadv(x, e + 2 * q + 1, f32), 0.f);
    }
    if (f32) {
        float4* op = (float4*)((float*)outp + e);
        op[0] = make_float4(v[0], v[1], v[2], v[3]);
        op[1] = make_float4(v[4], v[5], v[6], v[7]);
    } else {
        uint4 o;
        o.x = (u32)f2bf(v[0]) | ((u32)f2bf(v[1]) << 16);
        o.y = (u32)f2bf(v[2]) | ((u32)f2bf(v[3]) << 16);
        o.z = (u32)f2bf(v[4]) | ((u32)f2bf(v[5]) << 16);
        o.w = (u32)f2bf(v[6]) | ((u32)f2bf(v[7]) << 16);
        ((uint4*)outp)[i] = o;
    }
}

extern "C" void kernel_launch(void* const* d_in, const int* in_sizes, int n_in,
                              void* d_out, int out_size, void* d_ws, size_t ws_size,
                              hipStream_t stream) {
    const void* x     = d_in[0];
    const void* w_tm1 = d_in[1];
    const void* b_tm1 = d_in[2];
    const void* w_tr1 = d_in[3];
    const void* b_tr1 = d_in[4];
    const void* w_dc1 = d_in[5];
    const void* g1    = d_in[6];
    const void* be1   = d_in[7];
    const void* w_tm2 = d_in[8];
    const void* b_tm2 = d_in[9];
    const void* w_tr2 = d_in[10];
    const void* b_tr2 = d_in[11];
    const void* w_dc2 = d_in[12];
    const void* g2    = d_in[13];
    const void* be2   = d_in[14];

    char* wsb = (char*)d_ws;
    u16*   xT     = (u16*)wsb;                       // 8,388,608 (alias out1)
    u16*   raw    = (u16*)(wsb + 8388608);           // 8,388,608
    u16*   wTg1   = (u16*)(wsb + 16777216);          // 1,179,648
    u16*   wTg2   = (u16*)(wsb + 17956864);          // 1,179,648
    u16*   wT61   = (u16*)(wsb + 19136512);          //    73,728
    u16*   wT62   = (u16*)(wsb + 19210240);          //    73,728
    float* pstats = (float*)(wsb + 19283968);        //   131,072
    u32*   flag   = (u32*)(wsb + 19415040);          //        16
    u16*   out1   = xT;

    k_probe   <<<1, 256, 0, stream>>>((const u32*)x, flag);
    k_prep_all<<<2848, 256, 0, stream>>>(x, w_dc1, w_dc2, w_tm1, w_tr1, w_tm2, w_tr2,
                                         flag, xT, wTg1, wTg2, wT61, wT62);
    // ---- round 1 ----
    k_deform  <<<512, 512, 0, stream>>>(xT, wTg1, wT61, b_tm1, b_tr1, flag, raw, pstats);
    k_gn_relu <<<256, 256, 0, stream>>>(raw, pstats, g1, be1, flag, out1);
    // ---- round 2 ----
    k_deform  <<<512, 512, 0, stream>>>(out1, wTg2, wT62, b_tm2, b_tr2, flag, raw, pstats);
    k_gn_final<<<2048, 256, 0, stream>>>(raw, pstats, g2, be2, x, flag, d_out);
}